// Round 10
// baseline (10775.145 us; speedup 1.0000x reference)
//
#include <hip/hip_runtime.h>
#include <math.h>

#define BSZ 512
#define TT  100
#define NDD 10
#define DSS 6
#define INS 256
#define HID 256
#define CAT 2816   // INS*NDD + HID
#define KZ  320
#define NOUTP 320
#define NOUT 266
#define NBLK 256
#define NTHR 1024

typedef short sh8 __attribute__((ext_vector_type(8)));
typedef float f4  __attribute__((ext_vector_type(4)));
typedef unsigned int u4 __attribute__((ext_vector_type(4)));
typedef unsigned short ushort_t;

__device__ __forceinline__ float sigf(float x) { return 1.0f / (1.0f + expf(-x)); }

__device__ __forceinline__ ushort_t f2bf(float f) {
    union { float f; unsigned int u; } v; v.f = f;
    unsigned int r = (v.u + 0x7FFFu + ((v.u >> 16) & 1u)) >> 16;
    return (ushort_t)r;
}

#define MFMA(a, b, c) __builtin_amdgcn_mfma_f32_16x16x32_bf16((a), (b), (c), 0, 0, 0)
#define ALOAD(p)    __hip_atomic_load((p), __ATOMIC_RELAXED, __HIP_MEMORY_SCOPE_AGENT)
#define ASTORE(p,v) __hip_atomic_store((p), (v), __ATOMIC_RELAXED, __HIP_MEMORY_SCOPE_AGENT)

// ---------------------------------------------------------------------------
// Scoped DATA helpers — V3 (round-10).
// FAST = all 8 blocks of this group verified on ONE XCD. Data ops are PLAIN
// loads/stores: CDNA vL1 is write-through, so plain stores land in the XCD's
// L2 (dirty, never pushed to L3). Coherence is provided the way the compiler
// itself implements acquire: gbarT<FAST> ends with
// __builtin_amdgcn_fence(ACQUIRE, "agent"), which emits the buffer_inv cache
// invalidate -> the first load after every barrier misses L1 and reads the
// writers' dirty L2 lines. (Round-7/9 lesson: per-load sc0/nt bits do NOT
// reliably bypass a stale L1 — nt is only a replacement hint.)
// SLOW = agent scope (sc0 sc1 asm), byte-identical to the validated baseline.
// "=&v" earlyclobber is MANDATORY on async global_load outputs.
// ---------------------------------------------------------------------------
template<bool FAST>
__device__ __forceinline__ u4 aload16T(const unsigned int* p) {
    if constexpr (FAST) {
        return *(const u4*)p;
    } else {
        u4 r;
        asm volatile("global_load_dwordx4 %0, %1, off sc0 sc1\n\ts_waitcnt vmcnt(0)"
                     : "=&v"(r) : "v"(p) : "memory");
        return r;
    }
}

template<bool FAST>
__device__ __forceinline__ void aload16x4T(f4* a, const float* p0, const float* p1,
                                           const float* p2, const float* p3) {
    if constexpr (FAST) {
        a[0] = *(const f4*)p0;
        a[1] = *(const f4*)p1;
        a[2] = *(const f4*)p2;
        a[3] = *(const f4*)p3;
    } else {
        asm volatile(
            "global_load_dwordx4 %0, %4, off sc0 sc1\n\t"
            "global_load_dwordx4 %1, %5, off sc0 sc1\n\t"
            "global_load_dwordx4 %2, %6, off sc0 sc1\n\t"
            "global_load_dwordx4 %3, %7, off sc0 sc1\n\t"
            "s_waitcnt vmcnt(0)"
            : "=&v"(a[0]), "=&v"(a[1]), "=&v"(a[2]), "=&v"(a[3])
            : "v"(p0), "v"(p1), "v"(p2), "v"(p3)
            : "memory");
    }
}

// 8 strided scalar loads (stride = one partial buffer = 512*320 floats).
template<bool FAST>
__device__ __forceinline__ float loadf8T(const float* p) {
    const size_t S = (size_t)512 * 320;
    if constexpr (FAST) {
        float a0 = p[0],     a1 = p[S],     a2 = p[2 * S], a3 = p[3 * S];
        float a4 = p[4 * S], a5 = p[5 * S], a6 = p[6 * S], a7 = p[7 * S];
        return ((a0 + a1) + (a2 + a3)) + ((a4 + a5) + (a6 + a7));
    } else {
        float a0, a1, a2, a3, a4, a5, a6, a7;
        asm volatile(
            "global_load_dword %0, %8, off sc0 sc1\n\t"
            "global_load_dword %1, %9, off sc0 sc1\n\t"
            "global_load_dword %2, %10, off sc0 sc1\n\t"
            "global_load_dword %3, %11, off sc0 sc1\n\t"
            "global_load_dword %4, %12, off sc0 sc1\n\t"
            "global_load_dword %5, %13, off sc0 sc1\n\t"
            "global_load_dword %6, %14, off sc0 sc1\n\t"
            "global_load_dword %7, %15, off sc0 sc1\n\t"
            "s_waitcnt vmcnt(0)"
            : "=&v"(a0), "=&v"(a1), "=&v"(a2), "=&v"(a3),
              "=&v"(a4), "=&v"(a5), "=&v"(a6), "=&v"(a7)
            : "v"(p), "v"(p + S), "v"(p + 2 * S), "v"(p + 3 * S),
              "v"(p + 4 * S), "v"(p + 5 * S), "v"(p + 6 * S), "v"(p + 7 * S)
            : "memory");
        return ((a0 + a1) + (a2 + a3)) + ((a4 + a5) + (a6 + a7));
    }
}

template<bool FAST>
__device__ __forceinline__ void storeuT(unsigned int* p, unsigned int v) {
    if constexpr (FAST)
        *p = v;   // write-through L1 -> dirty in XCD L2
    else
        asm volatile("global_store_dword %0, %1, off sc0 sc1" :: "v"(p), "v"(v) : "memory");
}

template<bool FAST>
__device__ __forceinline__ void storefT(float* p, float v) {
    if constexpr (FAST)
        *p = v;
    else
        asm volatile("global_store_dword %0, %1, off sc0 sc1" :: "v"(p), "v"(v) : "memory");
}

// ---------------------------------------------------------------------------
// Precompute kernels (unchanged, validated)
// ---------------------------------------------------------------------------
__global__ __launch_bounds__(64) void k_fold(
    const float* __restrict__ W1, const float* __restrict__ Wd,
    const float* __restrict__ bd, const float* __restrict__ b1,
    ushort_t* __restrict__ Wzc, float* __restrict__ bfold)
{
    __shared__ float sW1[2560];
    __shared__ float sWd[INS * DSS];
    __shared__ float red[64];
    const int j = blockIdx.x;
    const int tid = threadIdx.x;
    for (int f = tid; f < INS * DSS; f += 64) sWd[f] = Wd[f];
    for (int f = tid; f < 2560; f += 64) sW1[f] = W1[(size_t)j * CAT + f];
    __syncthreads();
    if (tid < 60) {
        int n = tid / DSS, d = tid - n * DSS;
        float acc = 0.f;
        for (int i = 0; i < INS; ++i) acc += sW1[n * INS + i] * sWd[i * DSS + d];
        Wzc[j * KZ + tid] = f2bf(acc);
    } else {
        Wzc[j * KZ + tid] = 0;
    }
    for (int q = tid; q < HID; q += 64)
        Wzc[j * KZ + 64 + q] = f2bf(W1[(size_t)j * CAT + 2560 + q]);
    float acc = 0.f;
    for (int p = tid; p < 2560; p += 64) acc += sW1[p] * bd[p & (INS - 1)];
    red[tid] = acc;
    __syncthreads();
    for (int s = 32; s > 0; s >>= 1) {
        if (tid < s) red[tid] += red[tid + s];
        __syncthreads();
    }
    if (tid == 0) bfold[j] = b1[j] + red[0];
}

__global__ __launch_bounds__(256) void k_dfold(
    const float* __restrict__ desc, ushort_t* __restrict__ Dfold)
{
    int idx = blockIdx.x * 256 + threadIdx.x;
    int p = idx & 63;
    int tb = idx >> 6;
    int t = tb / BSZ;
    int b = tb - t * BSZ;
    float v = (p < 60) ? desc[(size_t)b * (TT * 60) + t * 60 + p] : 0.f;
    Dfold[idx] = f2bf(v);
}

__global__ __launch_bounds__(256) void k_prep_g(
    const float* __restrict__ Wih, const float* __restrict__ Whh,
    const float* __restrict__ bih, const float* __restrict__ bhh,
    ushort_t* __restrict__ Wg, float* __restrict__ bg)
{
    int idx = blockIdx.x * 256 + threadIdx.x;   // 1024*512
    int newr = idx >> 9, k = idx & 511;
    int j = newr >> 2, g = newr & 3;
    int src_row = g * 256 + j;
    float v = (k < 256) ? Wih[(size_t)src_row * INS + k]
                        : Whh[(size_t)src_row * HID + (k - 256)];
    Wg[idx] = f2bf(v);
    if (k == 0) bg[newr] = bih[src_row] + bhh[src_row];
}

__global__ __launch_bounds__(256) void k_prep_o(
    const float* __restrict__ W2, const float* __restrict__ Wv,
    ushort_t* __restrict__ Wout)
{
    int idx = blockIdx.x * 256 + threadIdx.x;   // 320*2816
    int r = idx / CAT, k = idx - r * CAT;
    float v = 0.f;
    if (r < 256) v = W2[(size_t)r * CAT + k];
    else if (r < NOUT) v = Wv[(size_t)(r - 256) * CAT + k];
    Wout[idx] = f2bf(v);
}

// ---------------------------------------------------------------------------
// GROUP barrier. Flag mechanism = agent scope, BYTE-IDENTICAL to the
// validated baseline (proven live-safe in round 7). Pre-bump __syncthreads
// drains vmcnt -> this block's plain stores are complete in the XCD L2
// before the flag bump (release). FAST adds the ACQUIRE half the way the
// compiler does: an agent-scope acquire fence (emits buffer_inv) executed by
// every wave after the closing barrier, so all subsequent loads miss stale
// L1/clean-L2 lines and read the writers' dirty L2 lines.
// ---------------------------------------------------------------------------
template<bool FAST>
__device__ __forceinline__ void gbarT(unsigned int* gb, int idx) {
    __syncthreads();
    if (threadIdx.x == 0) {
        unsigned int* p = gb + idx;
        __hip_atomic_fetch_add(p, 1u, __ATOMIC_RELAXED, __HIP_MEMORY_SCOPE_AGENT);
        while (ALOAD(p) < 8u)
            __builtin_amdgcn_s_sleep(1);
    }
    __syncthreads();
    if constexpr (FAST)
        __builtin_amdgcn_fence(__ATOMIC_ACQUIRE, "agent");
}

// ---------------------------------------------------------------------------
// Step loop, templated on DATA scope. Identical algorithm/layout to the
// validated kernel; only the data-op scope + (grp,s) derivation differ.
// ---------------------------------------------------------------------------
template<bool FAST>
__device__ void persist_body(
    const ushort_t* __restrict__ Wg, const float* __restrict__ bg,
    const ushort_t* __restrict__ Wzc, const float* __restrict__ bfold,
    const ushort_t* __restrict__ Wout, const float* __restrict__ b2,
    const float* __restrict__ bv, const ushort_t* __restrict__ Dfold,
    ushort_t* __restrict__ xh, float* __restrict__ partA, float* __restrict__ partB,
    float* __restrict__ out, unsigned int* __restrict__ bars,
    const int grp, const int s,
    ushort_t* sxh, ushort_t* sa, ushort_t* zt, float* sg, float* cl)
{
    const int tid = threadIdx.x;
    const int w = tid >> 6, l = tid & 63, quad = l >> 4, lr = l & 15;
    const int m0 = grp * 16;
    unsigned int* xh_u  = (unsigned int*)xh;    // row stride 384 uints
    unsigned int* sxh_u = (unsigned int*)sxh;
    unsigned int* sa_u  = (unsigned int*)sa;
    unsigned int* gb = bars + grp * 320;

    // init: zero own col-slice of group's 16 xh rows + own c slice
    for (int i = tid; i < 16 * 33; i += NTHR) cl[i] = 0.f;
    if (tid < 192) {
        int row = tid / 12, v = tid % 12;
        int q = s * 48 + v * 4;
        #pragma unroll
        for (int k = 0; k < 4; ++k)
            storeuT<FAST>(&xh_u[(size_t)(m0 + row) * 384 + q + k], 0u);
    }
    gbarT<FAST>(gb, 300);

    for (int t = 0; t < TT; ++t) {
        const int hcur  = 256 + (t & 1) * 256;
        const int hprev = 256 + ((t + 1) & 1) * 256;
        float*       pw = (t & 1) ? partB : partA;
        const float* pr = (t & 1) ? partA : partB;

        // ============ Phase A: reduce partials -> inp, out[t-1] ============
        if (t > 0) {
            int row = -1, chunk = 0;
            if (s < 6 && tid < 160)      { row = tid / 10; chunk = tid % 10; }
            else if (s == 6 && tid < 64) { row = tid >> 2; chunk = tid & 3; }
            if (row >= 0) {
                const int c0 = s * 40 + chunk * 4;
                f4 a[4], b[4];
                const float* base = &pr[((size_t)(m0 + row)) * 320 + c0];
                aload16x4T<FAST>(a, base + (size_t)0 * 512 * 320, base + (size_t)1 * 512 * 320,
                                    base + (size_t)2 * 512 * 320, base + (size_t)3 * 512 * 320);
                aload16x4T<FAST>(b, base + (size_t)4 * 512 * 320, base + (size_t)5 * 512 * 320,
                                    base + (size_t)6 * 512 * 320, base + (size_t)7 * 512 * 320);
                f4 sum = a[0] + a[1] + a[2] + a[3] + b[0] + b[1] + b[2] + b[3];
                f4 bb = *(const f4*)&b2[c0];
                unsigned int v0 = (unsigned int)f2bf(fmaxf(sum[0] + bb[0], 0.f))
                    | ((unsigned int)f2bf(fmaxf(sum[1] + bb[1], 0.f)) << 16);
                unsigned int v1 = (unsigned int)f2bf(fmaxf(sum[2] + bb[2], 0.f))
                    | ((unsigned int)f2bf(fmaxf(sum[3] + bb[3], 0.f)) << 16);
                storeuT<FAST>(&xh_u[(size_t)(m0 + row) * 384 + (c0 >> 1)], v0);
                storeuT<FAST>(&xh_u[(size_t)(m0 + row) * 384 + (c0 >> 1) + 1], v1);
            }
            if (s == 6 && tid >= 512 && tid < 672) {
                int k = tid - 512, r2 = k / 10, col = k - r2 * 10;
                float sum = loadf8T<FAST>(&pr[((size_t)(m0 + r2)) * 320 + 256 + col]);
                out[(size_t)(m0 + r2) * (TT * NDD) + (t - 1) * NDD + col] =
                    sigf(sum + bv[col]);
            }
            gbarT<FAST>(gb, 3 * t);
        }

        // ============ Phase B: gates slice + cell ==========================
        {
            int row = tid >> 6, q4 = tid & 63;
            const unsigned int* src = (q4 < 32)
                ? &xh_u[(size_t)(m0 + row) * 384 + q4 * 4]
                : &xh_u[(size_t)(m0 + row) * 384 + (hprev >> 1) + (q4 - 32) * 4];
            *(u4*)&sxh_u[row * 260 + q4 * 4] = aload16T<FAST>(src);
        }
        __syncthreads();
        {
            const int tile = w & 7, kh = w >> 3;
            f4 acc = {};
            const ushort_t* bp = Wg + (size_t)(s * 128 + tile * 16 + lr) * 512
                               + kh * 256 + quad * 8;
            const ushort_t* ap = &sxh[lr * 520 + kh * 256 + quad * 8];
            #pragma unroll
            for (int ks = 0; ks < 8; ++ks)
                acc = MFMA(*(const sh8*)(ap + ks * 32), *(const sh8*)(bp + ks * 32), acc);
            if (kh == 0) {
                #pragma unroll
                for (int r = 0; r < 4; ++r)
                    sg[(quad * 4 + r) * 132 + tile * 16 + lr] = acc[r];
            }
            __syncthreads();
            if (kh == 1) {
                #pragma unroll
                for (int r = 0; r < 4; ++r)
                    sg[(quad * 4 + r) * 132 + tile * 16 + lr] += acc[r];
            }
            __syncthreads();
            if (tid < 256) {
                int row = tid >> 4, jp = tid & 15;
                float g8[8];
                #pragma unroll
                for (int i = 0; i < 8; ++i)
                    g8[i] = sg[row * 132 + jp * 8 + i] + bg[s * 128 + jp * 8 + i];
                unsigned int pair = 0;
                #pragma unroll
                for (int h2 = 0; h2 < 2; ++h2) {
                    float ai = g8[h2 * 4 + 0], af = g8[h2 * 4 + 1];
                    float ag = g8[h2 * 4 + 2], ao = g8[h2 * 4 + 3];
                    int jc = jp * 2 + h2;
                    float cc = sigf(af) * cl[row * 33 + jc] + sigf(ai) * tanhf(ag);
                    cl[row * 33 + jc] = cc;
                    float hh = sigf(ao) * tanhf(cc);
                    pair |= ((unsigned int)f2bf(hh)) << (16 * h2);
                }
                storeuT<FAST>(&xh_u[(size_t)(m0 + row) * 384 + (hcur >> 1) + s * 16 + jp], pair);
            }
        }
        gbarT<FAST>(gb, 3 * t + 1);

        // ============ Phase C: z slice + OF partials =======================
        if (tid < 128) {
            int row = tid >> 3, v = tid & 7;
            *(u4*)&sa_u[row * 164 + v * 4] =
                *(const u4*)&Dfold[((size_t)t * BSZ + m0 + row) * 64 + v * 8];
        } else if (tid >= 256 && tid < 768) {
            int k = tid - 256;
            int row = k >> 5, v = k & 31;
            *(u4*)&sa_u[row * 164 + 32 + v * 4] =
                aload16T<FAST>(&xh_u[(size_t)(m0 + row) * 384 + (hcur >> 1) + v * 4]);
        }
        __syncthreads();
        for (int tl = w; tl < 22; tl += 16) {
            int n0g = s * 352 + tl * 16;
            f4 acc = {};
            const ushort_t* bp = Wzc + (size_t)(n0g + lr) * KZ + quad * 8;
            const ushort_t* ap = &sa[lr * 328 + quad * 8];
            #pragma unroll
            for (int ks = 0; ks < 10; ++ks)
                acc = MFMA(*(const sh8*)(ap + ks * 32), *(const sh8*)(bp + ks * 32), acc);
            float bia = bfold[n0g + lr];
            #pragma unroll
            for (int r = 0; r < 4; ++r)
                zt[(quad * 4 + r) * 360 + tl * 16 + lr] = f2bf(fmaxf(acc[r] + bia, 0.f));
        }
        __syncthreads();
        for (int tl = w; tl < 20; tl += 16) {
            int n0 = tl * 16;
            f4 acc = {};
            const ushort_t* bp = Wout + (size_t)(n0 + lr) * CAT + s * 352 + quad * 8;
            const ushort_t* ap = &zt[lr * 360 + quad * 8];
            #pragma unroll
            for (int ks = 0; ks < 11; ++ks)
                acc = MFMA(*(const sh8*)(ap + ks * 32), *(const sh8*)(bp + ks * 32), acc);
            #pragma unroll
            for (int r = 0; r < 4; ++r)
                storefT<FAST>(&pw[((size_t)(s * 512 + m0 + quad * 4 + r)) * 320 + n0 + lr],
                              acc[r]);
        }
        gbarT<FAST>(gb, 3 * t + 2);
    }

    // final out row (t = TT-1): partials in partB
    if (s == 6 && tid < 160) {
        int row = tid / 10, col = tid - row * 10;
        float sum = loadf8T<FAST>(&partB[((size_t)(m0 + row)) * 320 + 256 + col]);
        out[(size_t)(m0 + row) * (TT * NDD) + (TT - 1) * NDD + col] = sigf(sum + bv[col]);
    }
}

// ---------------------------------------------------------------------------
// Persistent kernel. Publishes real XCD id (HW_REG_XCC_ID), grid-syncs once,
// then all blocks deterministically agree on a (grp,s) mapping that co-locates
// each 8-block group on one XCD if the dispatch pattern allows:
//   M2 (round-robin XCD=bid%8):  s=(bid>>3)&7, grp=(bid&7)*4+(bid>>6)
//   M1 (chunked    XCD=bid/32):  s=bid&7,      grp=bid>>3
// Round-7 run confirmed the consensus engages the fast path on real dispatch.
// FAST groups exchange data via plain ops in their XCD's L2 with a per-barrier
// agent acquire fence (buffer_inv); others fall back to agent scope (sc0 sc1).
// ---------------------------------------------------------------------------
__global__ void __launch_bounds__(NTHR) k_persist(
    const ushort_t* __restrict__ Wg, const float* __restrict__ bg,
    const ushort_t* __restrict__ Wzc, const float* __restrict__ bfold,
    const ushort_t* __restrict__ Wout, const float* __restrict__ b2,
    const float* __restrict__ bv, const ushort_t* __restrict__ Dfold,
    ushort_t* __restrict__ xh,
    float* __restrict__ partA, float* __restrict__ partB,
    float* __restrict__ out, unsigned int* __restrict__ bars,
    unsigned int* __restrict__ xcds)
{
    __shared__ ushort_t sxh[16 * 520];
    __shared__ ushort_t sa[16 * 328];
    __shared__ ushort_t zt[16 * 360];
    __shared__ float    sg[16 * 132];
    __shared__ float    cl[16 * 33];
    __shared__ int      sflags[2];

    const int bid = blockIdx.x;
    const int tid = threadIdx.x;

    if (tid == 0) {
        unsigned int xcc;
        asm volatile("s_getreg_b32 %0, hwreg(HW_REG_XCC_ID, 0, 4)" : "=s"(xcc));
        ASTORE(&xcds[bid], xcc);
        sflags[0] = 1;   // m1ok
        sflags[1] = 1;   // m2ok
    }
    __syncthreads();
    // one-time grid barrier (agent scope) -> all xcds[] visible
    if (tid == 0) {
        unsigned int* p = bars + 32 * 320;
        __hip_atomic_fetch_add(p, 1u, __ATOMIC_RELAXED, __HIP_MEMORY_SCOPE_AGENT);
        while (ALOAD(p) < (unsigned int)NBLK)
            __builtin_amdgcn_s_sleep(2);
    }
    __syncthreads();
    // deterministic global consensus (same data -> same answer in every block)
    if (tid < 256) {
        unsigned int xa = ALOAD(&xcds[tid]);
        unsigned int xb = ALOAD(&xcds[tid & 7]);     // M2 group leader
        unsigned int xc = ALOAD(&xcds[tid & ~7]);    // M1 group leader
        if (xa != xb) atomicAnd(&sflags[1], 0);
        if (xa != xc) atomicAnd(&sflags[0], 0);
    }
    __syncthreads();
    const int m1ok = sflags[0], m2ok = sflags[1];
    int s, grp, fast;
    if (m2ok) {
        s = (bid >> 3) & 7; grp = (bid & 7) * 4 + (bid >> 6); fast = 1;
    } else if (m1ok) {
        s = bid & 7; grp = bid >> 3; fast = 1;
    } else {
        s = bid & 7; grp = bid >> 3;
        __syncthreads();
        if (tid == 0) sflags[0] = 1;
        __syncthreads();
        if (tid < 8) {
            unsigned int xa = ALOAD(&xcds[(bid & ~7) | tid]);
            unsigned int xb = ALOAD(&xcds[bid & ~7]);
            if (xa != xb) atomicAnd(&sflags[0], 0);
        }
        __syncthreads();
        fast = sflags[0];
    }

    if (fast)
        persist_body<true >(Wg, bg, Wzc, bfold, Wout, b2, bv, Dfold, xh,
                            partA, partB, out, bars, grp, s, sxh, sa, zt, sg, cl);
    else
        persist_body<false>(Wg, bg, Wzc, bfold, Wout, b2, bv, Dfold, xh,
                            partA, partB, out, bars, grp, s, sxh, sa, zt, sg, cl);
}

// ---------------------------------------------------------------------------
extern "C" void kernel_launch(void* const* d_in, const int* in_sizes, int n_in,
                              void* d_out, int out_size, void* d_ws, size_t ws_size,
                              hipStream_t stream)
{
    const float* desc = (const float*)d_in[0];
    const float* Wd   = (const float*)d_in[1];
    const float* bd   = (const float*)d_in[2];
    const float* W1   = (const float*)d_in[3];
    const float* b1   = (const float*)d_in[4];
    const float* W2   = (const float*)d_in[5];
    const float* b2   = (const float*)d_in[6];
    const float* Wv   = (const float*)d_in[7];
    const float* bv   = (const float*)d_in[8];
    const float* Wih  = (const float*)d_in[9];
    const float* Whh  = (const float*)d_in[10];
    const float* bih  = (const float*)d_in[11];
    const float* bhh  = (const float*)d_in[12];
    float* out = (float*)d_out;

    char* base = (char*)d_ws;
    size_t off = 0;
    auto alloc = [&](size_t bytes) -> char* {
        char* p = base + off;
        off = (off + bytes + 255) & ~(size_t)255;
        return p;
    };
    ushort_t*     Wzc   = (ushort_t*)alloc((size_t)CAT * KZ * 2);
    float*        bfold = (float*)alloc(CAT * 4);
    ushort_t*     Wg    = (ushort_t*)alloc(1024 * 512 * 2);
    float*        bg    = (float*)alloc(1024 * 4);
    ushort_t*     Wout  = (ushort_t*)alloc((size_t)NOUTP * CAT * 2);
    ushort_t*     Dfold = (ushort_t*)alloc((size_t)TT * BSZ * 64 * 2);
    ushort_t*     xh    = (ushort_t*)alloc((size_t)BSZ * 768 * 2);
    float*        partA = (float*)alloc((size_t)8 * BSZ * NOUTP * 4);
    float*        partB = (float*)alloc((size_t)8 * BSZ * NOUTP * 4);
    unsigned int* bars  = (unsigned int*)alloc((32 * 320 + 64) * 4);
    unsigned int* xcds  = (unsigned int*)alloc(NBLK * 4);

    hipMemsetAsync(bars, 0, (32 * 320 + 64) * 4, stream);

    k_fold  <<<CAT, 64, 0, stream>>>(W1, Wd, bd, b1, Wzc, bfold);
    k_dfold <<<(TT * BSZ * 64) / 256, 256, 0, stream>>>(desc, Dfold);
    k_prep_g<<<(1024 * 512) / 256, 256, 0, stream>>>(Wih, Whh, bih, bhh, Wg, bg);
    k_prep_o<<<(NOUTP * CAT) / 256, 256, 0, stream>>>(W2, Wv, Wout);

    void* args[] = {
        (void*)&Wg, (void*)&bg, (void*)&Wzc, (void*)&bfold, (void*)&Wout,
        (void*)&b2, (void*)&bv, (void*)&Dfold, (void*)&xh,
        (void*)&partA, (void*)&partB, (void*)&out, (void*)&bars, (void*)&xcds
    };
    hipLaunchCooperativeKernel((const void*)k_persist, dim3(NBLK), dim3(NTHR),
                               args, 0, stream);
}

// Round 11
// 2318.630 us; speedup vs baseline: 4.6472x; 4.6472x over previous
//
#include <hip/hip_runtime.h>
#include <math.h>

#define BSZ 512
#define TT  100
#define NDD 10
#define DSS 6
#define INS 256
#define HID 256
#define CAT 2816   // INS*NDD + HID
#define KZ  320
#define NOUTP 320
#define NOUT 266
#define NBLK 256
#define NTHR 1024

typedef short sh8 __attribute__((ext_vector_type(8)));
typedef float f4  __attribute__((ext_vector_type(4)));
typedef unsigned int u4 __attribute__((ext_vector_type(4)));
typedef unsigned short ushort_t;

__device__ __forceinline__ float sigf(float x) { return 1.0f / (1.0f + expf(-x)); }

__device__ __forceinline__ ushort_t f2bf(float f) {
    union { float f; unsigned int u; } v; v.f = f;
    unsigned int r = (v.u + 0x7FFFu + ((v.u >> 16) & 1u)) >> 16;
    return (ushort_t)r;
}

#define MFMA(a, b, c) __builtin_amdgcn_mfma_f32_16x16x32_bf16((a), (b), (c), 0, 0, 0)
#define ALOAD(p)    __hip_atomic_load((p), __ATOMIC_RELAXED, __HIP_MEMORY_SCOPE_AGENT)
#define ASTORE(p,v) __hip_atomic_store((p), (v), __ATOMIC_RELAXED, __HIP_MEMORY_SCOPE_AGENT)

// ---------------------------------------------------------------------------
// Scoped DATA helpers — V4 (round-11).
// FAST = all 8 blocks of this group verified on ONE XCD. Data ops are PLAIN
// loads/stores: CDNA vL1 is write-through, so plain stores land dirty in the
// XCD's L2 (round-10 PASS proves this). Reader-side coherence is an L1-ONLY
// invalidate in the barrier: `buffer_inv sc0` (SE scope = vL1 only).
// Round-10 lesson: the agent acquire fence lowers to `buffer_inv sc1`
// (device scope) which ALSO dumps the XCD L2 -> 4.6 MB of weights refetched
// from L3/HBM every barrier = 28 us/fence = 10.6 ms total. Same-XCD traffic
// can never have a stale L2 (it's shared), so sc0 is sufficient AND cheap.
// SLOW = agent scope (sc0 sc1 asm), byte-identical to the validated baseline.
// "=&v" earlyclobber is MANDATORY on async global_load outputs.
// ---------------------------------------------------------------------------
template<bool FAST>
__device__ __forceinline__ u4 aload16T(const unsigned int* p) {
    if constexpr (FAST) {
        return *(const u4*)p;
    } else {
        u4 r;
        asm volatile("global_load_dwordx4 %0, %1, off sc0 sc1\n\ts_waitcnt vmcnt(0)"
                     : "=&v"(r) : "v"(p) : "memory");
        return r;
    }
}

template<bool FAST>
__device__ __forceinline__ void aload16x4T(f4* a, const float* p0, const float* p1,
                                           const float* p2, const float* p3) {
    if constexpr (FAST) {
        a[0] = *(const f4*)p0;
        a[1] = *(const f4*)p1;
        a[2] = *(const f4*)p2;
        a[3] = *(const f4*)p3;
    } else {
        asm volatile(
            "global_load_dwordx4 %0, %4, off sc0 sc1\n\t"
            "global_load_dwordx4 %1, %5, off sc0 sc1\n\t"
            "global_load_dwordx4 %2, %6, off sc0 sc1\n\t"
            "global_load_dwordx4 %3, %7, off sc0 sc1\n\t"
            "s_waitcnt vmcnt(0)"
            : "=&v"(a[0]), "=&v"(a[1]), "=&v"(a[2]), "=&v"(a[3])
            : "v"(p0), "v"(p1), "v"(p2), "v"(p3)
            : "memory");
    }
}

// 8 strided scalar loads (stride = one partial buffer = 512*320 floats).
template<bool FAST>
__device__ __forceinline__ float loadf8T(const float* p) {
    const size_t S = (size_t)512 * 320;
    if constexpr (FAST) {
        float a0 = p[0],     a1 = p[S],     a2 = p[2 * S], a3 = p[3 * S];
        float a4 = p[4 * S], a5 = p[5 * S], a6 = p[6 * S], a7 = p[7 * S];
        return ((a0 + a1) + (a2 + a3)) + ((a4 + a5) + (a6 + a7));
    } else {
        float a0, a1, a2, a3, a4, a5, a6, a7;
        asm volatile(
            "global_load_dword %0, %8, off sc0 sc1\n\t"
            "global_load_dword %1, %9, off sc0 sc1\n\t"
            "global_load_dword %2, %10, off sc0 sc1\n\t"
            "global_load_dword %3, %11, off sc0 sc1\n\t"
            "global_load_dword %4, %12, off sc0 sc1\n\t"
            "global_load_dword %5, %13, off sc0 sc1\n\t"
            "global_load_dword %6, %14, off sc0 sc1\n\t"
            "global_load_dword %7, %15, off sc0 sc1\n\t"
            "s_waitcnt vmcnt(0)"
            : "=&v"(a0), "=&v"(a1), "=&v"(a2), "=&v"(a3),
              "=&v"(a4), "=&v"(a5), "=&v"(a6), "=&v"(a7)
            : "v"(p), "v"(p + S), "v"(p + 2 * S), "v"(p + 3 * S),
              "v"(p + 4 * S), "v"(p + 5 * S), "v"(p + 6 * S), "v"(p + 7 * S)
            : "memory");
        return ((a0 + a1) + (a2 + a3)) + ((a4 + a5) + (a6 + a7));
    }
}

template<bool FAST>
__device__ __forceinline__ void storeuT(unsigned int* p, unsigned int v) {
    if constexpr (FAST)
        *p = v;   // write-through L1 -> dirty in XCD L2
    else
        asm volatile("global_store_dword %0, %1, off sc0 sc1" :: "v"(p), "v"(v) : "memory");
}

template<bool FAST>
__device__ __forceinline__ void storefT(float* p, float v) {
    if constexpr (FAST)
        *p = v;
    else
        asm volatile("global_store_dword %0, %1, off sc0 sc1" :: "v"(p), "v"(v) : "memory");
}

// ---------------------------------------------------------------------------
// Precompute kernels (unchanged, validated)
// ---------------------------------------------------------------------------
__global__ __launch_bounds__(64) void k_fold(
    const float* __restrict__ W1, const float* __restrict__ Wd,
    const float* __restrict__ bd, const float* __restrict__ b1,
    ushort_t* __restrict__ Wzc, float* __restrict__ bfold)
{
    __shared__ float sW1[2560];
    __shared__ float sWd[INS * DSS];
    __shared__ float red[64];
    const int j = blockIdx.x;
    const int tid = threadIdx.x;
    for (int f = tid; f < INS * DSS; f += 64) sWd[f] = Wd[f];
    for (int f = tid; f < 2560; f += 64) sW1[f] = W1[(size_t)j * CAT + f];
    __syncthreads();
    if (tid < 60) {
        int n = tid / DSS, d = tid - n * DSS;
        float acc = 0.f;
        for (int i = 0; i < INS; ++i) acc += sW1[n * INS + i] * sWd[i * DSS + d];
        Wzc[j * KZ + tid] = f2bf(acc);
    } else {
        Wzc[j * KZ + tid] = 0;
    }
    for (int q = tid; q < HID; q += 64)
        Wzc[j * KZ + 64 + q] = f2bf(W1[(size_t)j * CAT + 2560 + q]);
    float acc = 0.f;
    for (int p = tid; p < 2560; p += 64) acc += sW1[p] * bd[p & (INS - 1)];
    red[tid] = acc;
    __syncthreads();
    for (int s = 32; s > 0; s >>= 1) {
        if (tid < s) red[tid] += red[tid + s];
        __syncthreads();
    }
    if (tid == 0) bfold[j] = b1[j] + red[0];
}

__global__ __launch_bounds__(256) void k_dfold(
    const float* __restrict__ desc, ushort_t* __restrict__ Dfold)
{
    int idx = blockIdx.x * 256 + threadIdx.x;
    int p = idx & 63;
    int tb = idx >> 6;
    int t = tb / BSZ;
    int b = tb - t * BSZ;
    float v = (p < 60) ? desc[(size_t)b * (TT * 60) + t * 60 + p] : 0.f;
    Dfold[idx] = f2bf(v);
}

__global__ __launch_bounds__(256) void k_prep_g(
    const float* __restrict__ Wih, const float* __restrict__ Whh,
    const float* __restrict__ bih, const float* __restrict__ bhh,
    ushort_t* __restrict__ Wg, float* __restrict__ bg)
{
    int idx = blockIdx.x * 256 + threadIdx.x;   // 1024*512
    int newr = idx >> 9, k = idx & 511;
    int j = newr >> 2, g = newr & 3;
    int src_row = g * 256 + j;
    float v = (k < 256) ? Wih[(size_t)src_row * INS + k]
                        : Whh[(size_t)src_row * HID + (k - 256)];
    Wg[idx] = f2bf(v);
    if (k == 0) bg[newr] = bih[src_row] + bhh[src_row];
}

__global__ __launch_bounds__(256) void k_prep_o(
    const float* __restrict__ W2, const float* __restrict__ Wv,
    ushort_t* __restrict__ Wout)
{
    int idx = blockIdx.x * 256 + threadIdx.x;   // 320*2816
    int r = idx / CAT, k = idx - r * CAT;
    float v = 0.f;
    if (r < 256) v = W2[(size_t)r * CAT + k];
    else if (r < NOUT) v = Wv[(size_t)(r - 256) * CAT + k];
    Wout[idx] = f2bf(v);
}

// ---------------------------------------------------------------------------
// GROUP barrier. Flag mechanism = agent scope, BYTE-IDENTICAL to the
// validated baseline (live-safe since round 7). Pre-bump __syncthreads
// drains vmcnt -> this block's plain stores are complete in the XCD L2
// before the flag bump (release). FAST acquire half = L1-ONLY invalidate
// (`buffer_inv sc0`, SE scope): subsequent loads miss vL1 and read the
// writers' dirty XCD-L2 lines. L2 is shared within the XCD -> never stale
// for this traffic -> no L2 invalidate needed (round-10's 28us/fence bug).
// ---------------------------------------------------------------------------
template<bool FAST>
__device__ __forceinline__ void gbarT(unsigned int* gb, int idx) {
    __syncthreads();
    if (threadIdx.x == 0) {
        unsigned int* p = gb + idx;
        __hip_atomic_fetch_add(p, 1u, __ATOMIC_RELAXED, __HIP_MEMORY_SCOPE_AGENT);
        while (ALOAD(p) < 8u)
            __builtin_amdgcn_s_sleep(1);
    }
    __syncthreads();
    if constexpr (FAST)
        asm volatile("s_waitcnt vmcnt(0)\n\tbuffer_inv sc0" ::: "memory");
}

// ---------------------------------------------------------------------------
// Step loop, templated on DATA scope. Identical algorithm/layout to the
// validated kernel; only the data-op scope + (grp,s) derivation differ.
// ---------------------------------------------------------------------------
template<bool FAST>
__device__ void persist_body(
    const ushort_t* __restrict__ Wg, const float* __restrict__ bg,
    const ushort_t* __restrict__ Wzc, const float* __restrict__ bfold,
    const ushort_t* __restrict__ Wout, const float* __restrict__ b2,
    const float* __restrict__ bv, const ushort_t* __restrict__ Dfold,
    ushort_t* __restrict__ xh, float* __restrict__ partA, float* __restrict__ partB,
    float* __restrict__ out, unsigned int* __restrict__ bars,
    const int grp, const int s,
    ushort_t* sxh, ushort_t* sa, ushort_t* zt, float* sg, float* cl)
{
    const int tid = threadIdx.x;
    const int w = tid >> 6, l = tid & 63, quad = l >> 4, lr = l & 15;
    const int m0 = grp * 16;
    unsigned int* xh_u  = (unsigned int*)xh;    // row stride 384 uints
    unsigned int* sxh_u = (unsigned int*)sxh;
    unsigned int* sa_u  = (unsigned int*)sa;
    unsigned int* gb = bars + grp * 320;

    // init: zero own col-slice of group's 16 xh rows + own c slice
    for (int i = tid; i < 16 * 33; i += NTHR) cl[i] = 0.f;
    if (tid < 192) {
        int row = tid / 12, v = tid % 12;
        int q = s * 48 + v * 4;
        #pragma unroll
        for (int k = 0; k < 4; ++k)
            storeuT<FAST>(&xh_u[(size_t)(m0 + row) * 384 + q + k], 0u);
    }
    gbarT<FAST>(gb, 300);

    for (int t = 0; t < TT; ++t) {
        const int hcur  = 256 + (t & 1) * 256;
        const int hprev = 256 + ((t + 1) & 1) * 256;
        float*       pw = (t & 1) ? partB : partA;
        const float* pr = (t & 1) ? partA : partB;

        // ============ Phase A: reduce partials -> inp, out[t-1] ============
        if (t > 0) {
            int row = -1, chunk = 0;
            if (s < 6 && tid < 160)      { row = tid / 10; chunk = tid % 10; }
            else if (s == 6 && tid < 64) { row = tid >> 2; chunk = tid & 3; }
            if (row >= 0) {
                const int c0 = s * 40 + chunk * 4;
                f4 a[4], b[4];
                const float* base = &pr[((size_t)(m0 + row)) * 320 + c0];
                aload16x4T<FAST>(a, base + (size_t)0 * 512 * 320, base + (size_t)1 * 512 * 320,
                                    base + (size_t)2 * 512 * 320, base + (size_t)3 * 512 * 320);
                aload16x4T<FAST>(b, base + (size_t)4 * 512 * 320, base + (size_t)5 * 512 * 320,
                                    base + (size_t)6 * 512 * 320, base + (size_t)7 * 512 * 320);
                f4 sum = a[0] + a[1] + a[2] + a[3] + b[0] + b[1] + b[2] + b[3];
                f4 bb = *(const f4*)&b2[c0];
                unsigned int v0 = (unsigned int)f2bf(fmaxf(sum[0] + bb[0], 0.f))
                    | ((unsigned int)f2bf(fmaxf(sum[1] + bb[1], 0.f)) << 16);
                unsigned int v1 = (unsigned int)f2bf(fmaxf(sum[2] + bb[2], 0.f))
                    | ((unsigned int)f2bf(fmaxf(sum[3] + bb[3], 0.f)) << 16);
                storeuT<FAST>(&xh_u[(size_t)(m0 + row) * 384 + (c0 >> 1)], v0);
                storeuT<FAST>(&xh_u[(size_t)(m0 + row) * 384 + (c0 >> 1) + 1], v1);
            }
            if (s == 6 && tid >= 512 && tid < 672) {
                int k = tid - 512, r2 = k / 10, col = k - r2 * 10;
                float sum = loadf8T<FAST>(&pr[((size_t)(m0 + r2)) * 320 + 256 + col]);
                out[(size_t)(m0 + r2) * (TT * NDD) + (t - 1) * NDD + col] =
                    sigf(sum + bv[col]);
            }
            gbarT<FAST>(gb, 3 * t);
        }

        // ============ Phase B: gates slice + cell ==========================
        {
            int row = tid >> 6, q4 = tid & 63;
            const unsigned int* src = (q4 < 32)
                ? &xh_u[(size_t)(m0 + row) * 384 + q4 * 4]
                : &xh_u[(size_t)(m0 + row) * 384 + (hprev >> 1) + (q4 - 32) * 4];
            *(u4*)&sxh_u[row * 260 + q4 * 4] = aload16T<FAST>(src);
        }
        __syncthreads();
        {
            const int tile = w & 7, kh = w >> 3;
            f4 acc = {};
            const ushort_t* bp = Wg + (size_t)(s * 128 + tile * 16 + lr) * 512
                               + kh * 256 + quad * 8;
            const ushort_t* ap = &sxh[lr * 520 + kh * 256 + quad * 8];
            #pragma unroll
            for (int ks = 0; ks < 8; ++ks)
                acc = MFMA(*(const sh8*)(ap + ks * 32), *(const sh8*)(bp + ks * 32), acc);
            if (kh == 0) {
                #pragma unroll
                for (int r = 0; r < 4; ++r)
                    sg[(quad * 4 + r) * 132 + tile * 16 + lr] = acc[r];
            }
            __syncthreads();
            if (kh == 1) {
                #pragma unroll
                for (int r = 0; r < 4; ++r)
                    sg[(quad * 4 + r) * 132 + tile * 16 + lr] += acc[r];
            }
            __syncthreads();
            if (tid < 256) {
                int row = tid >> 4, jp = tid & 15;
                float g8[8];
                #pragma unroll
                for (int i = 0; i < 8; ++i)
                    g8[i] = sg[row * 132 + jp * 8 + i] + bg[s * 128 + jp * 8 + i];
                unsigned int pair = 0;
                #pragma unroll
                for (int h2 = 0; h2 < 2; ++h2) {
                    float ai = g8[h2 * 4 + 0], af = g8[h2 * 4 + 1];
                    float ag = g8[h2 * 4 + 2], ao = g8[h2 * 4 + 3];
                    int jc = jp * 2 + h2;
                    float cc = sigf(af) * cl[row * 33 + jc] + sigf(ai) * tanhf(ag);
                    cl[row * 33 + jc] = cc;
                    float hh = sigf(ao) * tanhf(cc);
                    pair |= ((unsigned int)f2bf(hh)) << (16 * h2);
                }
                storeuT<FAST>(&xh_u[(size_t)(m0 + row) * 384 + (hcur >> 1) + s * 16 + jp], pair);
            }
        }
        gbarT<FAST>(gb, 3 * t + 1);

        // ============ Phase C: z slice + OF partials =======================
        if (tid < 128) {
            int row = tid >> 3, v = tid & 7;
            *(u4*)&sa_u[row * 164 + v * 4] =
                *(const u4*)&Dfold[((size_t)t * BSZ + m0 + row) * 64 + v * 8];
        } else if (tid >= 256 && tid < 768) {
            int k = tid - 256;
            int row = k >> 5, v = k & 31;
            *(u4*)&sa_u[row * 164 + 32 + v * 4] =
                aload16T<FAST>(&xh_u[(size_t)(m0 + row) * 384 + (hcur >> 1) + v * 4]);
        }
        __syncthreads();
        for (int tl = w; tl < 22; tl += 16) {
            int n0g = s * 352 + tl * 16;
            f4 acc = {};
            const ushort_t* bp = Wzc + (size_t)(n0g + lr) * KZ + quad * 8;
            const ushort_t* ap = &sa[lr * 328 + quad * 8];
            #pragma unroll
            for (int ks = 0; ks < 10; ++ks)
                acc = MFMA(*(const sh8*)(ap + ks * 32), *(const sh8*)(bp + ks * 32), acc);
            float bia = bfold[n0g + lr];
            #pragma unroll
            for (int r = 0; r < 4; ++r)
                zt[(quad * 4 + r) * 360 + tl * 16 + lr] = f2bf(fmaxf(acc[r] + bia, 0.f));
        }
        __syncthreads();
        for (int tl = w; tl < 20; tl += 16) {
            int n0 = tl * 16;
            f4 acc = {};
            const ushort_t* bp = Wout + (size_t)(n0 + lr) * CAT + s * 352 + quad * 8;
            const ushort_t* ap = &zt[lr * 360 + quad * 8];
            #pragma unroll
            for (int ks = 0; ks < 11; ++ks)
                acc = MFMA(*(const sh8*)(ap + ks * 32), *(const sh8*)(bp + ks * 32), acc);
            #pragma unroll
            for (int r = 0; r < 4; ++r)
                storefT<FAST>(&pw[((size_t)(s * 512 + m0 + quad * 4 + r)) * 320 + n0 + lr],
                              acc[r]);
        }
        gbarT<FAST>(gb, 3 * t + 2);
    }

    // final out row (t = TT-1): partials in partB
    if (s == 6 && tid < 160) {
        int row = tid / 10, col = tid - row * 10;
        float sum = loadf8T<FAST>(&partB[((size_t)(m0 + row)) * 320 + 256 + col]);
        out[(size_t)(m0 + row) * (TT * NDD) + (TT - 1) * NDD + col] = sigf(sum + bv[col]);
    }
}

// ---------------------------------------------------------------------------
// Persistent kernel. Publishes real XCD id (HW_REG_XCC_ID), grid-syncs once,
// then all blocks deterministically agree on a (grp,s) mapping that co-locates
// each 8-block group on one XCD if the dispatch pattern allows:
//   M2 (round-robin XCD=bid%8):  s=(bid>>3)&7, grp=(bid&7)*4+(bid>>6)
//   M1 (chunked    XCD=bid/32):  s=bid&7,      grp=bid>>3
// Round-7/10 runs confirmed the consensus engages the fast path on real
// dispatch and that plain stores + reader-side invalidate is correct.
// FAST groups exchange data via plain ops in their XCD's L2 with a per-barrier
// L1-only invalidate (buffer_inv sc0); others fall back to agent scope.
// ---------------------------------------------------------------------------
__global__ void __launch_bounds__(NTHR) k_persist(
    const ushort_t* __restrict__ Wg, const float* __restrict__ bg,
    const ushort_t* __restrict__ Wzc, const float* __restrict__ bfold,
    const ushort_t* __restrict__ Wout, const float* __restrict__ b2,
    const float* __restrict__ bv, const ushort_t* __restrict__ Dfold,
    ushort_t* __restrict__ xh,
    float* __restrict__ partA, float* __restrict__ partB,
    float* __restrict__ out, unsigned int* __restrict__ bars,
    unsigned int* __restrict__ xcds)
{
    __shared__ ushort_t sxh[16 * 520];
    __shared__ ushort_t sa[16 * 328];
    __shared__ ushort_t zt[16 * 360];
    __shared__ float    sg[16 * 132];
    __shared__ float    cl[16 * 33];
    __shared__ int      sflags[2];

    const int bid = blockIdx.x;
    const int tid = threadIdx.x;

    if (tid == 0) {
        unsigned int xcc;
        asm volatile("s_getreg_b32 %0, hwreg(HW_REG_XCC_ID, 0, 4)" : "=s"(xcc));
        ASTORE(&xcds[bid], xcc);
        sflags[0] = 1;   // m1ok
        sflags[1] = 1;   // m2ok
    }
    __syncthreads();
    // one-time grid barrier (agent scope) -> all xcds[] visible
    if (tid == 0) {
        unsigned int* p = bars + 32 * 320;
        __hip_atomic_fetch_add(p, 1u, __ATOMIC_RELAXED, __HIP_MEMORY_SCOPE_AGENT);
        while (ALOAD(p) < (unsigned int)NBLK)
            __builtin_amdgcn_s_sleep(2);
    }
    __syncthreads();
    // deterministic global consensus (same data -> same answer in every block)
    if (tid < 256) {
        unsigned int xa = ALOAD(&xcds[tid]);
        unsigned int xb = ALOAD(&xcds[tid & 7]);     // M2 group leader
        unsigned int xc = ALOAD(&xcds[tid & ~7]);    // M1 group leader
        if (xa != xb) atomicAnd(&sflags[1], 0);
        if (xa != xc) atomicAnd(&sflags[0], 0);
    }
    __syncthreads();
    const int m1ok = sflags[0], m2ok = sflags[1];
    int s, grp, fast;
    if (m2ok) {
        s = (bid >> 3) & 7; grp = (bid & 7) * 4 + (bid >> 6); fast = 1;
    } else if (m1ok) {
        s = bid & 7; grp = bid >> 3; fast = 1;
    } else {
        s = bid & 7; grp = bid >> 3;
        __syncthreads();
        if (tid == 0) sflags[0] = 1;
        __syncthreads();
        if (tid < 8) {
            unsigned int xa = ALOAD(&xcds[(bid & ~7) | tid]);
            unsigned int xb = ALOAD(&xcds[bid & ~7]);
            if (xa != xb) atomicAnd(&sflags[0], 0);
        }
        __syncthreads();
        fast = sflags[0];
    }

    if (fast)
        persist_body<true >(Wg, bg, Wzc, bfold, Wout, b2, bv, Dfold, xh,
                            partA, partB, out, bars, grp, s, sxh, sa, zt, sg, cl);
    else
        persist_body<false>(Wg, bg, Wzc, bfold, Wout, b2, bv, Dfold, xh,
                            partA, partB, out, bars, grp, s, sxh, sa, zt, sg, cl);
}

// ---------------------------------------------------------------------------
extern "C" void kernel_launch(void* const* d_in, const int* in_sizes, int n_in,
                              void* d_out, int out_size, void* d_ws, size_t ws_size,
                              hipStream_t stream)
{
    const float* desc = (const float*)d_in[0];
    const float* Wd   = (const float*)d_in[1];
    const float* bd   = (const float*)d_in[2];
    const float* W1   = (const float*)d_in[3];
    const float* b1   = (const float*)d_in[4];
    const float* W2   = (const float*)d_in[5];
    const float* b2   = (const float*)d_in[6];
    const float* Wv   = (const float*)d_in[7];
    const float* bv   = (const float*)d_in[8];
    const float* Wih  = (const float*)d_in[9];
    const float* Whh  = (const float*)d_in[10];
    const float* bih  = (const float*)d_in[11];
    const float* bhh  = (const float*)d_in[12];
    float* out = (float*)d_out;

    char* base = (char*)d_ws;
    size_t off = 0;
    auto alloc = [&](size_t bytes) -> char* {
        char* p = base + off;
        off = (off + bytes + 255) & ~(size_t)255;
        return p;
    };
    ushort_t*     Wzc   = (ushort_t*)alloc((size_t)CAT * KZ * 2);
    float*        bfold = (float*)alloc(CAT * 4);
    ushort_t*     Wg    = (ushort_t*)alloc(1024 * 512 * 2);
    float*        bg    = (float*)alloc(1024 * 4);
    ushort_t*     Wout  = (ushort_t*)alloc((size_t)NOUTP * CAT * 2);
    ushort_t*     Dfold = (ushort_t*)alloc((size_t)TT * BSZ * 64 * 2);
    ushort_t*     xh    = (ushort_t*)alloc((size_t)BSZ * 768 * 2);
    float*        partA = (float*)alloc((size_t)8 * BSZ * NOUTP * 4);
    float*        partB = (float*)alloc((size_t)8 * BSZ * NOUTP * 4);
    unsigned int* bars  = (unsigned int*)alloc((32 * 320 + 64) * 4);
    unsigned int* xcds  = (unsigned int*)alloc(NBLK * 4);

    hipMemsetAsync(bars, 0, (32 * 320 + 64) * 4, stream);

    k_fold  <<<CAT, 64, 0, stream>>>(W1, Wd, bd, b1, Wzc, bfold);
    k_dfold <<<(TT * BSZ * 64) / 256, 256, 0, stream>>>(desc, Dfold);
    k_prep_g<<<(1024 * 512) / 256, 256, 0, stream>>>(Wih, Whh, bih, bhh, Wg, bg);
    k_prep_o<<<(NOUTP * CAT) / 256, 256, 0, stream>>>(W2, Wv, Wout);

    void* args[] = {
        (void*)&Wg, (void*)&bg, (void*)&Wzc, (void*)&bfold, (void*)&Wout,
        (void*)&b2, (void*)&bv, (void*)&Dfold, (void*)&xh,
        (void*)&partA, (void*)&partB, (void*)&out, (void*)&bars, (void*)&xcds
    };
    hipLaunchCooperativeKernel((const void*)k_persist, dim3(NBLK), dim3(NTHR),
                               args, 0, stream);
}